// Round 8
// baseline (107.653 us; speedup 1.0000x reference)
//
#include <hip/hip_runtime.h>
#include <math.h>

// Two-dispatch structure with a STRICT hot/cold function split:
//  - Kernel 1 (fourier_main): pure-f32 LEAF kernel (no calls anywhere in the
//    function -> natural <=64 VGPR -> 8 waves/SIMD, 2 blocks/CU). R6/R7's
//    regression mechanism was the __noinline__ f64 slow_exact call making the
//    kernel non-leaf: VGPR allocation covers the call graph (ocml f64 sincos
//    ~100+ VGPR), so cap-64 => spills / cap-128 => halved occupancy, ~2x.
//    Slow pairs: per-lane 32-bit mask (kFPW=32), stored unconditionally.
//  - Kernel 2 (combine_fix): per-point combine + rare exact-f64 replay of
//    masked pairs (f64 code isolated here), scale, mirror-write. No atomics.

namespace {
constexpr int kNpts = 32 * 32 * 32;   // 32768 frequency points
constexpr int kHalf = kNpts / 2;      // 16384 conj-unique points
constexpr int kNF = 1024;             // faces
constexpr int kThreads = 1024;        // 16 waves
constexpr int kWaves = 16;
constexpr int kFaceHalves = 2;
constexpr int kFPW = (kNF / kFaceHalves) / kWaves;   // 32 faces per wave
constexpr int kBlocks = (kHalf / 64) * kFaceHalves;  // 512 blocks
constexpr int kNumWaves = kBlocks * kWaves;          // 8192
// d_ws layout (offsets in 32-bit words):
//   [0..2)     f32 area partials (face-half 0, 1)
//   [256..)    partial grids: 2 * kHalf float2  (65536 words)
//   [65792..)  per-thread slow masks: kNumWaves*64 u32 (2 MB)
constexpr int kGridOffW = 256;
constexpr int kMaskOffW = kGridOffW + kFaceHalves * kHalf * 2;  // 65792
}

__device__ __forceinline__ float fract32(float x) {
#if __has_builtin(__builtin_amdgcn_fractf)
    return __builtin_amdgcn_fractf(x);
#else
    return x - floorf(x);
#endif
}

// ---- Kernel 1: LEAF, pure f32. In-block face prep (this half's 512 faces)
// + main Fourier sum. Near-degenerate pairs (product gate) contribute 0 and
// set a bit in the lane's mask. ----
__global__ __launch_bounds__(kThreads, 8) void fourier_main(
        const float* __restrict__ verts, const float* __restrict__ box,
        const int* __restrict__ faces, unsigned* __restrict__ wsu,
        const float* __restrict__ xi0, const float* __restrict__ xi1,
        const float* __restrict__ xi2) {
    const float INV_TWO_PI_F = 0.15915494f;
    const float TAUP_REV2 = 2.5330296e-5f;  // 1e-3 rad^2 in rev^2 (product gate)

    __shared__ float4 rec[kNF / kFaceHalves][3];  // 24 KB
    __shared__ float accR[kWaves][64];            // 4 KB
    __shared__ float accI[kWaves][64];            // 4 KB
    __shared__ float wsum[8];

    const int t = threadIdx.x;
    const int l = t & 63;                 // lane -> point within group
    const int w = t >> 6;                 // wave -> face subgroup
    const int pb = blockIdx.x & 255;      // point group [0,256)
    const int fh = blockIdx.x >> 8;       // face half

    // ---- prep: threads 0..511 build this half's 512 face records ----
    if (t < 512) {
        const int f = fh * 512 + t;
        const float lo0 = box[0], lo1 = box[2], lo2 = box[4];
        const int ia = faces[3 * f + 0], ib = faces[3 * f + 1], ic = faces[3 * f + 2];
        const float ax = verts[3 * ia + 0] - lo0, ay = verts[3 * ia + 1] - lo1, az = verts[3 * ia + 2] - lo2;
        const float bx = verts[3 * ib + 0] - lo0, by = verts[3 * ib + 1] - lo1, bz = verts[3 * ib + 2] - lo2;
        const float cx = verts[3 * ic + 0] - lo0, cy = verts[3 * ic + 1] - lo1, cz = verts[3 * ic + 2] - lo2;
        const float e1x = bx - ax, e1y = by - ay, e1z = bz - az;
        const float e2x = cx - ax, e2y = cy - ay, e2z = cz - az;
        const float crx = e1y * e2z - e1z * e2y;
        const float cry = e1z * e2x - e1x * e2z;
        const float crz = e1x * e2y - e1y * e2x;
        const float area = 0.5f * sqrtf(crx * crx + cry * cry + crz * crz);
        rec[t][0] = make_float4(ax, ay, az, bx);
        rec[t][1] = make_float4(by, bz, cx, cy);
        rec[t][2] = make_float4(cz, area * 0.025330296f, 0.0f, 0.0f);
        // wave-reduce area over waves 0..7 -> this half's area partial
        float a = area;
        a += __shfl_down(a, 32, 64);
        a += __shfl_down(a, 16, 64);
        a += __shfl_down(a, 8, 64);
        a += __shfl_down(a, 4, 64);
        a += __shfl_down(a, 2, 64);
        a += __shfl_down(a, 1, 64);
        if (l == 0) wsum[w] = a;
    }
    __syncthreads();
    if (t == 0 && pb == 0) {   // one block per half publishes its area partial
        float s = wsum[0];
#pragma unroll
        for (int j = 1; j < 8; ++j) s += wsum[j];
        ((float*)wsu)[fh] = s;
    }

    // ---- main loop: wave w sums its 32 faces for point p ----
    const int p = pb * 64 + l;            // p in [0, kHalf)
    const int i2 = p & 31, i1 = (p >> 5) & 31, i0 = p >> 10;
    const float xxr = xi0[i0] * INV_TWO_PI_F;
    const float xyr = xi1[i1] * INV_TWO_PI_F;
    const float xzr = xi2[i2] * INV_TWO_PI_F;

    float re = 0.0f, im = 0.0f;
    unsigned slowMask = 0u;
    const int rbase = w * kFPW;

#pragma unroll 4
    for (int i = 0; i < kFPW; ++i) {
        const float4 q0 = rec[rbase + i][0];
        const float4 q1 = rec[rbase + i][1];
        const float4 q2 = rec[rbase + i][2];
        // phases in revolutions, f32 (F has O(1) derivatives; f32 phase noise
        // -> ~1e-5-level output error; denominators gated below)
        const float ra = fmaf(xzr, q0.z, fmaf(xyr, q0.y, xxr * q0.x));
        const float rb = fmaf(xzr, q1.y, fmaf(xyr, q1.x, xxr * q0.w));
        const float rc = fmaf(xzr, q2.x, fmaf(xyr, q1.w, xxr * q1.z));
        const float fdab = rb - ra, fdbc = rc - rb, fdca = ra - rc;
        const float d1 = fdab * fdca;   // rev^2 pair products (product gate)
        const float d2 = fdbc * fdab;
        const float d3 = fdca * fdbc;
        const float mn = fminf(fminf(fabsf(d1), fabsf(d2)), fabsf(d3));
        if (mn > TAUP_REV2) {
            // fast path: v_fract -> hw v_sin/v_cos (rev input), 1 rcp;
            // area/(4pi^2) folded into the reciprocal
            const float R3w = __builtin_amdgcn_rcpf(d1 * fdbc) * q2.y;
            const float r1 = fdbc * R3w, r2 = fdca * R3w, r3 = fdab * R3w;
            const float fa = fract32(ra);
            const float fb = fract32(rb);
            const float fc = fract32(rc);
            const float sa = __builtin_amdgcn_sinf(fa), ca = __builtin_amdgcn_cosf(fa);
            const float sb = __builtin_amdgcn_sinf(fb), cb = __builtin_amdgcn_cosf(fb);
            const float sc = __builtin_amdgcn_sinf(fc), cc = __builtin_amdgcn_cosf(fc);
            re = fmaf(cc, r3, fmaf(cb, r2, fmaf(ca, r1, re)));
            im = fmaf(-sc, r3, fmaf(-sb, r2, fmaf(-sa, r1, im)));
        } else {
            slowMask |= (1u << i);
        }
    }

    // per-thread mask store, unconditional (ws is poisoned every iteration)
    const int waveId = blockIdx.x * kWaves + w;
    wsu[kMaskOffW + waveId * 64 + l] = slowMask;

    // reduce 16 wave partials per point; write this half's partial grid
    accR[w][l] = re;
    accI[w][l] = im;
    __syncthreads();
    if (w == 0) {
        float R = accR[0][l], I = accI[0][l];
#pragma unroll
        for (int g = 1; g < kWaves; ++g) { R += accR[g][l]; I += accI[g][l]; }
        float2* pg = (float2*)(wsu + kGridOffW);
        pg[(size_t)fh * kHalf + p] = make_float2(R, I);
    }
}

// exact f64 replica of the reference's pair case value
__device__ __forceinline__ void pair_case_f64(double x1, double x2, double x3,
                                              double& vr, double& vi) {
    const double m = (x1 + x2) * 0.5;
    const double d = m - x3;
    double sm, cm, s3, c3;
    sincos(m, &sm, &cm);
    sincos(x3, &s3, &c3);
    vr = (sm + (cm - c3) / d) / d;
    vi = (cm + (s3 - sm) / d) / d;
}

// Exact f64 replica of the reference region logic for one (face, point) pair.
// Lives ONLY in kernel 2's call graph: the hot kernel stays leaf.
__device__ __noinline__ void slow_exact(
        int f, int p, const float* __restrict__ verts,
        const float* __restrict__ box, const int* __restrict__ faces,
        const float* __restrict__ xi0, const float* __restrict__ xi1,
        const float* __restrict__ xi2, float& cr, float& ci) {
    const double SEPS = __builtin_sqrt(1.19209e-07);  // matches float(np.sqrt(EPS))
    const double TWO_PI = 6.283185307179586;
    const double INV_TWO_PI = 0.15915494309189535;

    const int i2 = p & 31, i1 = (p >> 5) & 31, i0 = p >> 10;
    const double xxd = (double)xi0[i0] * INV_TWO_PI;
    const double xyd = (double)xi1[i1] * INV_TWO_PI;
    const double xzd = (double)xi2[i2] * INV_TWO_PI;
    const double lo0 = (double)box[0], lo1 = (double)box[2], lo2 = (double)box[4];
    const int ia = faces[3 * f + 0], ib = faces[3 * f + 1], ic = faces[3 * f + 2];
    const double ax = (double)verts[3 * ia + 0] - lo0, ay = (double)verts[3 * ia + 1] - lo1, az = (double)verts[3 * ia + 2] - lo2;
    const double bx = (double)verts[3 * ib + 0] - lo0, by = (double)verts[3 * ib + 1] - lo1, bz = (double)verts[3 * ib + 2] - lo2;
    const double cx = (double)verts[3 * ic + 0] - lo0, cy = (double)verts[3 * ic + 1] - lo1, cz = (double)verts[3 * ic + 2] - lo2;
    // f32 area exactly as the fast-path prep computes it
    const float axf = (float)ax, ayf = (float)ay, azf = (float)az;
    const float bxf = (float)bx, byf = (float)by, bzf = (float)bz;
    const float cxf = (float)cx, cyf = (float)cy, czf = (float)cz;
    const float e1x = bxf - axf, e1y = byf - ayf, e1z = bzf - azf;
    const float e2x = cxf - axf, e2y = cyf - ayf, e2z = czf - azf;
    const float crx = e1y * e2z - e1z * e2y;
    const float cry = e1z * e2x - e1x * e2z;
    const float crz = e1x * e2y - e1y * e2x;
    const float areaf = 0.5f * sqrtf(crx * crx + cry * cry + crz * crz);
    const double rad = fma(xzd, az, fma(xyd, ay, xxd * ax));
    const double rbd = fma(xzd, bz, fma(xyd, by, xxd * bx));
    const double rcd = fma(xzd, cz, fma(xyd, cy, xxd * cx));
    const double xa = rad * TWO_PI, xb = rbd * TWO_PI, xc = rcd * TWO_PI;
    const double dAB = xb - xa, dBC = xc - xb, dCA = xa - xc;
    const double aab = fabs(dAB), abc = fabs(dBC), aca = fabs(dCA);
    const bool s2 = aab < SEPS, s3 = abc < SEPS, s4 = aca < SEPS;
    const bool c2 = aab <= SEPS, c3 = abc <= SEPS, c4 = aca <= SEPS;
    const bool R1 = (s2 && s3) || (s3 && s4) || (s4 && s2);
    const bool R2 = c2 && !R1;
    const bool R3b = c3 && !R2 && !R1;
    const bool R4 = c4 && !R3b && !R2 && !R1;
    double vr, vi;
    if (R1) {
        const double m = ((xa + xb) + xc) / 3.0;
        double sm, cm;
        sincos(m, &sm, &cm);
        vr = cm / 2.0;
        vi = -sm / 2.0;
    } else if (R2) {
        pair_case_f64(xa, xb, xc, vr, vi);
    } else if (R3b) {
        pair_case_f64(xb, xc, xa, vr, vi);
    } else if (R4) {
        pair_case_f64(xc, xa, xb, vr, vi);
    } else {
        double sa, ca, sb, cb, sc, cc;
        sincos(xa, &sa, &ca);
        sincos(xb, &sb, &cb);
        sincos(xc, &sc, &cc);
        const double da = dAB * dCA, db = dBC * dAB, dc = dCA * dBC;
        vr = (ca / da + cb / db) + cc / dc;
        vi = -((sa / da + sb / db) + sc / dc);
    }
    cr = areaf * (float)vr;
    ci = areaf * (float)vi;
}

// ---- Kernel 2: combine + slow replay. One thread per point p: sum the two
// half-partials, scan this point's 32 mask words (coalesced, L2-warm),
// replay set bits in exact f64, scale by 2/meshar, mirror-write. ----
__global__ __launch_bounds__(64) void combine_fix(
        const float* __restrict__ verts, const float* __restrict__ box,
        const int* __restrict__ faces, const float* __restrict__ xi0,
        const float* __restrict__ xi1, const float* __restrict__ xi2,
        const unsigned* __restrict__ wsu, float* __restrict__ out,
        int interleaved) {
    const int pb = blockIdx.x;            // [0,256)
    const int l = threadIdx.x;            // [0,64)
    const int p = pb * 64 + l;

    const float2* pg = (const float2*)(wsu + kGridOffW);
    const float2 a = pg[p];
    const float2 b = pg[kHalf + p];
    float R = a.x + b.x;
    float I = a.y + b.y;

    // replay this point's slow pairs (mask layout: waveId*64 + l, where
    // waveId = (fh*256 + pb)*16 + w; face = fh*512 + w*32 + bit)
#pragma unroll
    for (int fh = 0; fh < 2; ++fh) {
        for (int w = 0; w < kWaves; ++w) {
            unsigned m = wsu[kMaskOffW + (((fh << 8) | pb) * kWaves + w) * 64 + l];
            while (m) {
                const int i = __builtin_ctz(m);
                m &= m - 1u;
                float cr, ci;
                slow_exact(fh * 512 + w * kFPW + i, p, verts, box, faces,
                           xi0, xi1, xi2, cr, ci);
                R += cr;
                I += ci;
            }
        }
    }

    const float* wsf = (const float*)wsu;
    const float inv2 = 2.0f / (wsf[0] + wsf[1]);
    R *= inv2;
    I *= inv2;
    const int q = kNpts - 1 - p;
    if (interleaved) {
        ((float2*)out)[p] = make_float2(R, I);
        ((float2*)out)[q] = make_float2(R, -I);
    } else {
        out[p] = R;
        out[q] = R;
    }
}

extern "C" void kernel_launch(void* const* d_in, const int* in_sizes, int n_in,
                              void* d_out, int out_size, void* d_ws, size_t ws_size,
                              hipStream_t stream) {
    const float* verts = (const float*)d_in[0];
    const float* box   = (const float*)d_in[1];
    const float* xi0v  = (const float*)d_in[2];
    const float* xi1v  = (const float*)d_in[3];
    const float* xi2v  = (const float*)d_in[4];
    const int*   faces = (const int*)d_in[5];
    unsigned* wsu = (unsigned*)d_ws;

    const int interleaved = (out_size == 2 * kNpts) ? 1 : 0;

    hipLaunchKernelGGL(fourier_main, dim3(kBlocks), dim3(kThreads), 0, stream,
                       verts, box, faces, wsu, xi0v, xi1v, xi2v);
    hipLaunchKernelGGL(combine_fix, dim3(kHalf / 64), dim3(64), 0, stream,
                       verts, box, faces, xi0v, xi1v, xi2v, wsu,
                       (float*)d_out, interleaved);
}

// Round 9
// 96.508 us; speedup vs baseline: 1.1155x; 1.1155x over previous
//
#include <hip/hip_runtime.h>
#include <math.h>

// Two-dispatch, strict hot/cold split, load-balanced replay:
//  - Kernel 1 (fourier_main): pure-f32 LEAF kernel, bounds (1024,4) — the
//    exact configuration the R5 duplication probe measured at 24.5us —
//    with the ballot/segment machinery replaced by a per-lane 32-bit mask
//    store (strictly less in-loop work). No f64, no calls.
//  - Kernel 2 (combine_fix): 4 scanner-threads per point, each scanning 8 of
//    the point's 32 mask words and replaying its bits in exact f64. Fixes
//    R8's failure mode (one thread serially replaying a clustered point's
//    ~dozens of slow faces at 1-wave occupancy -> ~25us by subtraction).
//    Private partials + deterministic 4-way LDS reduce, scale, mirror-write.

namespace {
constexpr int kNpts = 32 * 32 * 32;   // 32768 frequency points
constexpr int kHalf = kNpts / 2;      // 16384 conj-unique points
constexpr int kNF = 1024;             // faces
constexpr int kThreads = 1024;        // 16 waves
constexpr int kWaves = 16;
constexpr int kFaceHalves = 2;
constexpr int kFPW = (kNF / kFaceHalves) / kWaves;   // 32 faces per wave
constexpr int kBlocks = (kHalf / 64) * kFaceHalves;  // 512 blocks
constexpr int kNumWaves = kBlocks * kWaves;          // 8192
// d_ws layout (offsets in 32-bit words):
//   [0..2)     f32 area partials (face-half 0, 1)
//   [256..)    partial grids: 2 * kHalf float2  (65536 words)
//   [65792..)  per-thread slow masks: kNumWaves*64 u32 (2 MB)
constexpr int kGridOffW = 256;
constexpr int kMaskOffW = kGridOffW + kFaceHalves * kHalf * 2;  // 65792
}

__device__ __forceinline__ float fract32(float x) {
#if __has_builtin(__builtin_amdgcn_fractf)
    return __builtin_amdgcn_fractf(x);
#else
    return x - floorf(x);
#endif
}

// ---- Kernel 1: LEAF, pure f32. In-block face prep (this half's 512 faces)
// + main Fourier sum. Near-degenerate pairs (product gate) contribute 0 and
// set a bit in the lane's mask. ----
__global__ __launch_bounds__(kThreads, 4) void fourier_main(
        const float* __restrict__ verts, const float* __restrict__ box,
        const int* __restrict__ faces, unsigned* __restrict__ wsu,
        const float* __restrict__ xi0, const float* __restrict__ xi1,
        const float* __restrict__ xi2) {
    const float INV_TWO_PI_F = 0.15915494f;
    const float TAUP_REV2 = 2.5330296e-5f;  // 1e-3 rad^2 in rev^2 (product gate)

    __shared__ float4 rec[kNF / kFaceHalves][3];  // 24 KB
    __shared__ float accR[kWaves][64];            // 4 KB
    __shared__ float accI[kWaves][64];            // 4 KB
    __shared__ float wsum[8];

    const int t = threadIdx.x;
    const int l = t & 63;                 // lane -> point within group
    const int w = t >> 6;                 // wave -> face subgroup
    const int pb = blockIdx.x & 255;      // point group [0,256)
    const int fh = blockIdx.x >> 8;       // face half

    // ---- prep: threads 0..511 build this half's 512 face records ----
    if (t < 512) {
        const int f = fh * 512 + t;
        const float lo0 = box[0], lo1 = box[2], lo2 = box[4];
        const int ia = faces[3 * f + 0], ib = faces[3 * f + 1], ic = faces[3 * f + 2];
        const float ax = verts[3 * ia + 0] - lo0, ay = verts[3 * ia + 1] - lo1, az = verts[3 * ia + 2] - lo2;
        const float bx = verts[3 * ib + 0] - lo0, by = verts[3 * ib + 1] - lo1, bz = verts[3 * ib + 2] - lo2;
        const float cx = verts[3 * ic + 0] - lo0, cy = verts[3 * ic + 1] - lo1, cz = verts[3 * ic + 2] - lo2;
        const float e1x = bx - ax, e1y = by - ay, e1z = bz - az;
        const float e2x = cx - ax, e2y = cy - ay, e2z = cz - az;
        const float crx = e1y * e2z - e1z * e2y;
        const float cry = e1z * e2x - e1x * e2z;
        const float crz = e1x * e2y - e1y * e2x;
        const float area = 0.5f * sqrtf(crx * crx + cry * cry + crz * crz);
        rec[t][0] = make_float4(ax, ay, az, bx);
        rec[t][1] = make_float4(by, bz, cx, cy);
        rec[t][2] = make_float4(cz, area * 0.025330296f, 0.0f, 0.0f);
        // wave-reduce area over waves 0..7 -> this half's area partial
        float a = area;
        a += __shfl_down(a, 32, 64);
        a += __shfl_down(a, 16, 64);
        a += __shfl_down(a, 8, 64);
        a += __shfl_down(a, 4, 64);
        a += __shfl_down(a, 2, 64);
        a += __shfl_down(a, 1, 64);
        if (l == 0) wsum[w] = a;
    }
    __syncthreads();
    if (t == 0 && pb == 0) {   // one block per half publishes its area partial
        float s = wsum[0];
#pragma unroll
        for (int j = 1; j < 8; ++j) s += wsum[j];
        ((float*)wsu)[fh] = s;
    }

    // ---- main loop: wave w sums its 32 faces for point p ----
    const int p = pb * 64 + l;            // p in [0, kHalf)
    const int i2 = p & 31, i1 = (p >> 5) & 31, i0 = p >> 10;
    const float xxr = xi0[i0] * INV_TWO_PI_F;
    const float xyr = xi1[i1] * INV_TWO_PI_F;
    const float xzr = xi2[i2] * INV_TWO_PI_F;

    float re = 0.0f, im = 0.0f;
    unsigned slowMask = 0u;
    const int rbase = w * kFPW;

#pragma unroll 4
    for (int i = 0; i < kFPW; ++i) {
        const float4 q0 = rec[rbase + i][0];
        const float4 q1 = rec[rbase + i][1];
        const float4 q2 = rec[rbase + i][2];
        // phases in revolutions, f32 (F has O(1) derivatives; f32 phase noise
        // -> ~1e-5-level output error; denominators gated below)
        const float ra = fmaf(xzr, q0.z, fmaf(xyr, q0.y, xxr * q0.x));
        const float rb = fmaf(xzr, q1.y, fmaf(xyr, q1.x, xxr * q0.w));
        const float rc = fmaf(xzr, q2.x, fmaf(xyr, q1.w, xxr * q1.z));
        const float fdab = rb - ra, fdbc = rc - rb, fdca = ra - rc;
        const float d1 = fdab * fdca;   // rev^2 pair products (product gate)
        const float d2 = fdbc * fdab;
        const float d3 = fdca * fdbc;
        const float mn = fminf(fminf(fabsf(d1), fabsf(d2)), fabsf(d3));
        if (mn > TAUP_REV2) {
            // fast path: v_fract -> hw v_sin/v_cos (rev input), 1 rcp;
            // area/(4pi^2) folded into the reciprocal
            const float R3w = __builtin_amdgcn_rcpf(d1 * fdbc) * q2.y;
            const float r1 = fdbc * R3w, r2 = fdca * R3w, r3 = fdab * R3w;
            const float fa = fract32(ra);
            const float fb = fract32(rb);
            const float fc = fract32(rc);
            const float sa = __builtin_amdgcn_sinf(fa), ca = __builtin_amdgcn_cosf(fa);
            const float sb = __builtin_amdgcn_sinf(fb), cb = __builtin_amdgcn_cosf(fb);
            const float sc = __builtin_amdgcn_sinf(fc), cc = __builtin_amdgcn_cosf(fc);
            re = fmaf(cc, r3, fmaf(cb, r2, fmaf(ca, r1, re)));
            im = fmaf(-sc, r3, fmaf(-sb, r2, fmaf(-sa, r1, im)));
        } else {
            slowMask |= (1u << i);
        }
    }

    // per-thread mask store, unconditional (ws is poisoned every iteration)
    const int waveId = blockIdx.x * kWaves + w;
    wsu[kMaskOffW + waveId * 64 + l] = slowMask;

    // reduce 16 wave partials per point; write this half's partial grid
    accR[w][l] = re;
    accI[w][l] = im;
    __syncthreads();
    if (w == 0) {
        float R = accR[0][l], I = accI[0][l];
#pragma unroll
        for (int g = 1; g < kWaves; ++g) { R += accR[g][l]; I += accI[g][l]; }
        float2* pg = (float2*)(wsu + kGridOffW);
        pg[(size_t)fh * kHalf + p] = make_float2(R, I);
    }
}

// exact f64 replica of the reference's pair case value
__device__ __forceinline__ void pair_case_f64(double x1, double x2, double x3,
                                              double& vr, double& vi) {
    const double m = (x1 + x2) * 0.5;
    const double d = m - x3;
    double sm, cm, s3, c3;
    sincos(m, &sm, &cm);
    sincos(x3, &s3, &c3);
    vr = (sm + (cm - c3) / d) / d;
    vi = (cm + (s3 - sm) / d) / d;
}

// Exact f64 replica of the reference region logic for one (face, point) pair.
// Lives ONLY in kernel 2's call graph: the hot kernel stays leaf.
__device__ __noinline__ void slow_exact(
        int f, int p, const float* __restrict__ verts,
        const float* __restrict__ box, const int* __restrict__ faces,
        const float* __restrict__ xi0, const float* __restrict__ xi1,
        const float* __restrict__ xi2, float& cr, float& ci) {
    const double SEPS = __builtin_sqrt(1.19209e-07);  // matches float(np.sqrt(EPS))
    const double TWO_PI = 6.283185307179586;
    const double INV_TWO_PI = 0.15915494309189535;

    const int i2 = p & 31, i1 = (p >> 5) & 31, i0 = p >> 10;
    const double xxd = (double)xi0[i0] * INV_TWO_PI;
    const double xyd = (double)xi1[i1] * INV_TWO_PI;
    const double xzd = (double)xi2[i2] * INV_TWO_PI;
    const double lo0 = (double)box[0], lo1 = (double)box[2], lo2 = (double)box[4];
    const int ia = faces[3 * f + 0], ib = faces[3 * f + 1], ic = faces[3 * f + 2];
    const double ax = (double)verts[3 * ia + 0] - lo0, ay = (double)verts[3 * ia + 1] - lo1, az = (double)verts[3 * ia + 2] - lo2;
    const double bx = (double)verts[3 * ib + 0] - lo0, by = (double)verts[3 * ib + 1] - lo1, bz = (double)verts[3 * ib + 2] - lo2;
    const double cx = (double)verts[3 * ic + 0] - lo0, cy = (double)verts[3 * ic + 1] - lo1, cz = (double)verts[3 * ic + 2] - lo2;
    // f32 area exactly as the fast-path prep computes it
    const float axf = (float)ax, ayf = (float)ay, azf = (float)az;
    const float bxf = (float)bx, byf = (float)by, bzf = (float)bz;
    const float cxf = (float)cx, cyf = (float)cy, czf = (float)cz;
    const float e1x = bxf - axf, e1y = byf - ayf, e1z = bzf - azf;
    const float e2x = cxf - axf, e2y = cyf - ayf, e2z = czf - azf;
    const float crx = e1y * e2z - e1z * e2y;
    const float cry = e1z * e2x - e1x * e2z;
    const float crz = e1x * e2y - e1y * e2x;
    const float areaf = 0.5f * sqrtf(crx * crx + cry * cry + crz * crz);
    const double rad = fma(xzd, az, fma(xyd, ay, xxd * ax));
    const double rbd = fma(xzd, bz, fma(xyd, by, xxd * bx));
    const double rcd = fma(xzd, cz, fma(xyd, cy, xxd * cx));
    const double xa = rad * TWO_PI, xb = rbd * TWO_PI, xc = rcd * TWO_PI;
    const double dAB = xb - xa, dBC = xc - xb, dCA = xa - xc;
    const double aab = fabs(dAB), abc = fabs(dBC), aca = fabs(dCA);
    const bool s2 = aab < SEPS, s3 = abc < SEPS, s4 = aca < SEPS;
    const bool c2 = aab <= SEPS, c3 = abc <= SEPS, c4 = aca <= SEPS;
    const bool R1 = (s2 && s3) || (s3 && s4) || (s4 && s2);
    const bool R2 = c2 && !R1;
    const bool R3b = c3 && !R2 && !R1;
    const bool R4 = c4 && !R3b && !R2 && !R1;
    double vr, vi;
    if (R1) {
        const double m = ((xa + xb) + xc) / 3.0;
        double sm, cm;
        sincos(m, &sm, &cm);
        vr = cm / 2.0;
        vi = -sm / 2.0;
    } else if (R2) {
        pair_case_f64(xa, xb, xc, vr, vi);
    } else if (R3b) {
        pair_case_f64(xb, xc, xa, vr, vi);
    } else if (R4) {
        pair_case_f64(xc, xa, xb, vr, vi);
    } else {
        double sa, ca, sb, cb, sc, cc;
        sincos(xa, &sa, &ca);
        sincos(xb, &sb, &cb);
        sincos(xc, &sc, &cc);
        const double da = dAB * dCA, db = dBC * dAB, dc = dCA * dBC;
        vr = (ca / da + cb / db) + cc / dc;
        vi = -((sa / da + sb / db) + sc / dc);
    }
    cr = areaf * (float)vr;
    ci = areaf * (float)vi;
}

// ---- Kernel 2: combine + balanced slow replay. 256 blocks x 256 threads.
// Thread (j,l): scanner j in [0,4) handles 8 of point (pb*64+l)'s 32 mask
// words, replaying set bits in exact f64. Private partials -> deterministic
// 4-way LDS reduce -> scale by 2/meshar -> mirror-write. ----
__global__ __launch_bounds__(256) void combine_fix(
        const float* __restrict__ verts, const float* __restrict__ box,
        const int* __restrict__ faces, const float* __restrict__ xi0,
        const float* __restrict__ xi1, const float* __restrict__ xi2,
        const unsigned* __restrict__ wsu, float* __restrict__ out,
        int interleaved) {
    __shared__ float corr[256][2];
    const int pb = blockIdx.x;            // [0,256)
    const int tid = threadIdx.x;          // [0,256)
    const int l = tid & 63;               // point lane
    const int j = tid >> 6;               // scanner [0,4)
    const int p = pb * 64 + l;

    float crA = 0.0f, ciA = 0.0f;
    // fw = fh*16 + w in [0,32); scanner j takes fw = j, j+4, ..., j+28
    for (int u = 0; u < 8; ++u) {
        const int fw = u * 4 + j;
        const int fh = fw >> 4, w = fw & 15;
        unsigned m = wsu[kMaskOffW + (((fh << 8) | pb) * kWaves + w) * 64 + l];
        while (m) {
            const int i = __builtin_ctz(m);
            m &= m - 1u;
            float cr, ci;
            slow_exact(fh * 512 + w * kFPW + i, p, verts, box, faces,
                       xi0, xi1, xi2, cr, ci);
            crA += cr;
            ciA += ci;
        }
    }
    corr[tid][0] = crA;
    corr[tid][1] = ciA;
    __syncthreads();

    if (tid < 64) {
        const float2* pg = (const float2*)(wsu + kGridOffW);
        const float2 a = pg[p];
        const float2 b = pg[kHalf + p];
        float R = a.x + b.x;
        float I = a.y + b.y;
#pragma unroll
        for (int g = 0; g < 4; ++g) {
            R += corr[g * 64 + l][0];
            I += corr[g * 64 + l][1];
        }
        const float* wsf = (const float*)wsu;
        const float inv2 = 2.0f / (wsf[0] + wsf[1]);
        R *= inv2;
        I *= inv2;
        const int q = kNpts - 1 - p;
        if (interleaved) {
            ((float2*)out)[p] = make_float2(R, I);
            ((float2*)out)[q] = make_float2(R, -I);
        } else {
            out[p] = R;
            out[q] = R;
        }
    }
}

extern "C" void kernel_launch(void* const* d_in, const int* in_sizes, int n_in,
                              void* d_out, int out_size, void* d_ws, size_t ws_size,
                              hipStream_t stream) {
    const float* verts = (const float*)d_in[0];
    const float* box   = (const float*)d_in[1];
    const float* xi0v  = (const float*)d_in[2];
    const float* xi1v  = (const float*)d_in[3];
    const float* xi2v  = (const float*)d_in[4];
    const int*   faces = (const int*)d_in[5];
    unsigned* wsu = (unsigned*)d_ws;

    const int interleaved = (out_size == 2 * kNpts) ? 1 : 0;

    hipLaunchKernelGGL(fourier_main, dim3(kBlocks), dim3(kThreads), 0, stream,
                       verts, box, faces, wsu, xi0v, xi1v, xi2v);
    hipLaunchKernelGGL(combine_fix, dim3(kHalf / 64), dim3(256), 0, stream,
                       verts, box, faces, xi0v, xi1v, xi2v, wsu,
                       (float*)d_out, interleaved);
}

// Round 10
// 91.904 us; speedup vs baseline: 1.1714x; 1.0501x over previous
//
#include <hip/hip_runtime.h>
#include <math.h>

// Single-dispatch fused kernel (R6 structure — best measured, 90.6us) with the
// two warts removed:
//  - hot loop is a pure-f32 LEAF region: slow pairs set a bit in a per-lane
//    64-bit register mask (kFPW=64). No LDS atomics, no calls, no list, no
//    overflow path.
//  - post-loop, each lane replays its own mask bits via __noinline__
//    slow_exact (exact f64 reference region logic), then the normal 16-wave
//    LDS reduce + 2/meshar scale + mirror write directly to out.
// No workspace use, no memset, no atomics: block = 64 points x all 1024 faces.

namespace {
constexpr int kNpts = 32 * 32 * 32;   // 32768 frequency points
constexpr int kHalf = kNpts / 2;      // 16384 conj-unique points
constexpr int kNF = 1024;             // faces
constexpr int kThreads = 1024;        // 16 waves
constexpr int kWaves = 16;
constexpr int kFPW = kNF / kWaves;    // 64 faces per wave
constexpr int kBlocks = kHalf / 64;   // 256 blocks = one per 64-point group
}

__device__ __forceinline__ float fract32(float x) {
#if __has_builtin(__builtin_amdgcn_fractf)
    return __builtin_amdgcn_fractf(x);
#else
    return x - floorf(x);
#endif
}

// exact f64 replica of the reference's pair case value
__device__ __forceinline__ void pair_case_f64(double x1, double x2, double x3,
                                              double& vr, double& vi) {
    const double m = (x1 + x2) * 0.5;
    const double d = m - x3;
    double sm, cm, s3, c3;
    sincos(m, &sm, &cm);
    sincos(x3, &s3, &c3);
    vr = (sm + (cm - c3) / d) / d;
    vi = (cm + (s3 - sm) / d) / d;
}

// Exact f64 replica of the reference region logic for one (face, point) pair.
// Called only AFTER the hot loop.
__device__ __noinline__ void slow_exact(
        int f, int p, const float* __restrict__ verts,
        const float* __restrict__ box, const int* __restrict__ faces,
        const float* __restrict__ xi0, const float* __restrict__ xi1,
        const float* __restrict__ xi2, float& cr, float& ci) {
    const double SEPS = __builtin_sqrt(1.19209e-07);  // matches float(np.sqrt(EPS))
    const double TWO_PI = 6.283185307179586;
    const double INV_TWO_PI = 0.15915494309189535;

    const int i2 = p & 31, i1 = (p >> 5) & 31, i0 = p >> 10;
    const double xxd = (double)xi0[i0] * INV_TWO_PI;
    const double xyd = (double)xi1[i1] * INV_TWO_PI;
    const double xzd = (double)xi2[i2] * INV_TWO_PI;
    const double lo0 = (double)box[0], lo1 = (double)box[2], lo2 = (double)box[4];
    const int ia = faces[3 * f + 0], ib = faces[3 * f + 1], ic = faces[3 * f + 2];
    const double ax = (double)verts[3 * ia + 0] - lo0, ay = (double)verts[3 * ia + 1] - lo1, az = (double)verts[3 * ia + 2] - lo2;
    const double bx = (double)verts[3 * ib + 0] - lo0, by = (double)verts[3 * ib + 1] - lo1, bz = (double)verts[3 * ib + 2] - lo2;
    const double cx = (double)verts[3 * ic + 0] - lo0, cy = (double)verts[3 * ic + 1] - lo1, cz = (double)verts[3 * ic + 2] - lo2;
    // f32 area exactly as the fast-path prep computes it
    const float axf = (float)ax, ayf = (float)ay, azf = (float)az;
    const float bxf = (float)bx, byf = (float)by, bzf = (float)bz;
    const float cxf = (float)cx, cyf = (float)cy, czf = (float)cz;
    const float e1x = bxf - axf, e1y = byf - ayf, e1z = bzf - azf;
    const float e2x = cxf - axf, e2y = cyf - ayf, e2z = czf - azf;
    const float crx = e1y * e2z - e1z * e2y;
    const float cry = e1z * e2x - e1x * e2z;
    const float crz = e1x * e2y - e1y * e2x;
    const float areaf = 0.5f * sqrtf(crx * crx + cry * cry + crz * crz);
    const double rad = fma(xzd, az, fma(xyd, ay, xxd * ax));
    const double rbd = fma(xzd, bz, fma(xyd, by, xxd * bx));
    const double rcd = fma(xzd, cz, fma(xyd, cy, xxd * cx));
    const double xa = rad * TWO_PI, xb = rbd * TWO_PI, xc = rcd * TWO_PI;
    const double dAB = xb - xa, dBC = xc - xb, dCA = xa - xc;
    const double aab = fabs(dAB), abc = fabs(dBC), aca = fabs(dCA);
    const bool s2 = aab < SEPS, s3 = abc < SEPS, s4 = aca < SEPS;
    const bool c2 = aab <= SEPS, c3 = abc <= SEPS, c4 = aca <= SEPS;
    const bool R1 = (s2 && s3) || (s3 && s4) || (s4 && s2);
    const bool R2 = c2 && !R1;
    const bool R3b = c3 && !R2 && !R1;
    const bool R4 = c4 && !R3b && !R2 && !R1;
    double vr, vi;
    if (R1) {
        const double m = ((xa + xb) + xc) / 3.0;
        double sm, cm;
        sincos(m, &sm, &cm);
        vr = cm / 2.0;
        vi = -sm / 2.0;
    } else if (R2) {
        pair_case_f64(xa, xb, xc, vr, vi);
    } else if (R3b) {
        pair_case_f64(xb, xc, xa, vr, vi);
    } else if (R4) {
        pair_case_f64(xc, xa, xb, vr, vi);
    } else {
        double sa, ca, sb, cb, sc, cc;
        sincos(xa, &sa, &ca);
        sincos(xb, &sb, &cb);
        sincos(xc, &sc, &cc);
        const double da = dAB * dCA, db = dBC * dAB, dc = dCA * dBC;
        vr = (ca / da + cb / db) + cc / dc;
        vi = -((sa / da + sb / db) + sc / dc);
    }
    cr = areaf * (float)vr;
    ci = areaf * (float)vi;
}

__global__ __launch_bounds__(kThreads, 4) void fourier_all(
        const float* __restrict__ verts, const float* __restrict__ box,
        const int* __restrict__ faces, const float* __restrict__ xi0,
        const float* __restrict__ xi1, const float* __restrict__ xi2,
        float* __restrict__ out, int interleaved) {
    const float INV_TWO_PI_F = 0.15915494f;
    const float TAUP_REV2 = 2.5330296e-5f;  // 1e-3 rad^2 in rev^2 (product gate)

    __shared__ float4 rec[kNF][3];        // 48 KB: per-face {a,b,c coords, w}
    __shared__ float accR[kWaves][64];    // 4 KB
    __shared__ float accI[kWaves][64];    // 4 KB
    __shared__ float wsum[kWaves];
    __shared__ float meshar_sh;

    const int t = threadIdx.x;
    const int l = t & 63;                 // lane -> point within group
    const int w = t >> 6;                 // wave -> face subgroup
    const int pb = blockIdx.x;            // point group [0,256)

    // ---- in-block face prep: thread t builds face t (all 1024 faces) ----
    {
        const int f = t;
        const float lo0 = box[0], lo1 = box[2], lo2 = box[4];
        const int ia = faces[3 * f + 0], ib = faces[3 * f + 1], ic = faces[3 * f + 2];
        const float ax = verts[3 * ia + 0] - lo0, ay = verts[3 * ia + 1] - lo1, az = verts[3 * ia + 2] - lo2;
        const float bx = verts[3 * ib + 0] - lo0, by = verts[3 * ib + 1] - lo1, bz = verts[3 * ib + 2] - lo2;
        const float cx = verts[3 * ic + 0] - lo0, cy = verts[3 * ic + 1] - lo1, cz = verts[3 * ic + 2] - lo2;
        const float e1x = bx - ax, e1y = by - ay, e1z = bz - az;
        const float e2x = cx - ax, e2y = cy - ay, e2z = cz - az;
        const float crx = e1y * e2z - e1z * e2y;
        const float cry = e1z * e2x - e1x * e2z;
        const float crz = e1x * e2y - e1y * e2x;
        const float area = 0.5f * sqrtf(crx * crx + cry * cry + crz * crz);
        rec[f][0] = make_float4(ax, ay, az, bx);
        rec[f][1] = make_float4(by, bz, cx, cy);
        rec[f][2] = make_float4(cz, area * 0.025330296f, 0.0f, 0.0f);
        // wave-reduce area; 16 wave partials -> meshar
        float a = area;
        a += __shfl_down(a, 32, 64);
        a += __shfl_down(a, 16, 64);
        a += __shfl_down(a, 8, 64);
        a += __shfl_down(a, 4, 64);
        a += __shfl_down(a, 2, 64);
        a += __shfl_down(a, 1, 64);
        if (l == 0) wsum[w] = a;
    }
    __syncthreads();
    if (t == 0) {
        float s = wsum[0];
#pragma unroll
        for (int j = 1; j < kWaves; ++j) s += wsum[j];
        meshar_sh = s;
    }

    // ---- hot loop (LEAF f32): wave w sums faces [w*64, w*64+64) for point p;
    // near-degenerate pairs set a bit in the lane's 64-bit mask ----
    const int p = pb * 64 + l;            // p in [0, kHalf)
    const int i2 = p & 31, i1 = (p >> 5) & 31, i0 = p >> 10;
    const float xxr = xi0[i0] * INV_TWO_PI_F;
    const float xyr = xi1[i1] * INV_TWO_PI_F;
    const float xzr = xi2[i2] * INV_TWO_PI_F;

    float re = 0.0f, im = 0.0f;
    unsigned long long slowMask = 0ull;
    const int fbase = w * kFPW;

#pragma unroll 4
    for (int i = 0; i < kFPW; ++i) {
        const float4 q0 = rec[fbase + i][0];
        const float4 q1 = rec[fbase + i][1];
        const float4 q2 = rec[fbase + i][2];
        // phases in revolutions, f32 (F has O(1) derivatives; f32 phase noise
        // -> ~1e-5-level output error; denominators gated below)
        const float ra = fmaf(xzr, q0.z, fmaf(xyr, q0.y, xxr * q0.x));
        const float rb = fmaf(xzr, q1.y, fmaf(xyr, q1.x, xxr * q0.w));
        const float rc = fmaf(xzr, q2.x, fmaf(xyr, q1.w, xxr * q1.z));
        const float fdab = rb - ra, fdbc = rc - rb, fdca = ra - rc;
        const float d1 = fdab * fdca;   // rev^2 pair products (product gate)
        const float d2 = fdbc * fdab;
        const float d3 = fdca * fdbc;
        const float mn = fminf(fminf(fabsf(d1), fabsf(d2)), fabsf(d3));
        if (mn > TAUP_REV2) {
            // fast path: v_fract -> hw v_sin/v_cos (rev input), 1 rcp;
            // area/(4pi^2) folded into the reciprocal
            const float R3w = __builtin_amdgcn_rcpf(d1 * fdbc) * q2.y;
            const float r1 = fdbc * R3w, r2 = fdca * R3w, r3 = fdab * R3w;
            const float fa = fract32(ra);
            const float fb = fract32(rb);
            const float fc = fract32(rc);
            const float sa = __builtin_amdgcn_sinf(fa), ca = __builtin_amdgcn_cosf(fa);
            const float sb = __builtin_amdgcn_sinf(fb), cb = __builtin_amdgcn_cosf(fb);
            const float sc = __builtin_amdgcn_sinf(fc), cc = __builtin_amdgcn_cosf(fc);
            re = fmaf(cc, r3, fmaf(cb, r2, fmaf(ca, r1, re)));
            im = fmaf(-sc, r3, fmaf(-sb, r2, fmaf(-sa, r1, im)));
        } else {
            slowMask |= (1ull << i);
        }
    }

    // ---- per-lane replay of this lane's slow pairs (rare; exact f64) ----
    if (slowMask) {
        unsigned long long m = slowMask;
        do {
            const int i = (int)__builtin_ctzll(m);
            m &= m - 1ull;
            float cr, ci;
            slow_exact(fbase + i, p, verts, box, faces, xi0, xi1, xi2, cr, ci);
            re += cr;
            im += ci;
        } while (m);
    }

    accR[w][l] = re;
    accI[w][l] = im;
    __syncthreads();

    // ---- final reduce + scale + mirror write ----
    if (t < 64) {
        float R = accR[0][l], I = accI[0][l];
#pragma unroll
        for (int g = 1; g < kWaves; ++g) { R += accR[g][l]; I += accI[g][l]; }
        const float inv2 = 2.0f / meshar_sh;
        R *= inv2;
        I *= inv2;
        const int q = kNpts - 1 - p;
        if (interleaved) {
            ((float2*)out)[p] = make_float2(R, I);
            ((float2*)out)[q] = make_float2(R, -I);
        } else {
            out[p] = R;
            out[q] = R;
        }
    }
}

extern "C" void kernel_launch(void* const* d_in, const int* in_sizes, int n_in,
                              void* d_out, int out_size, void* d_ws, size_t ws_size,
                              hipStream_t stream) {
    const float* verts = (const float*)d_in[0];
    const float* box   = (const float*)d_in[1];
    const float* xi0v  = (const float*)d_in[2];
    const float* xi1v  = (const float*)d_in[3];
    const float* xi2v  = (const float*)d_in[4];
    const int*   faces = (const int*)d_in[5];
    (void)d_ws; (void)ws_size;

    const int interleaved = (out_size == 2 * kNpts) ? 1 : 0;

    hipLaunchKernelGGL(fourier_all, dim3(kBlocks), dim3(kThreads), 0, stream,
                       verts, box, faces, xi0v, xi1v, xi2v,
                       (float*)d_out, interleaved);
}

// Round 11
// 90.138 us; speedup vs baseline: 1.1943x; 1.0196x over previous
//
#include <hip/hip_runtime.h>
#include <math.h>

// Z-recurrence version. Phase at (i0,i1,i2) is linear in i2 with step = vz
// revolutions per vertex (xi2[k]=(2k-31)*pi, box [0,1]). Each thread owns 4
// consecutive i2 points: full trig once per face, then 3 complex rotations by
// per-face constants cos/sin(2*pi*fract(vz)) (exact identity). Diffs/gate
// update incrementally. Cuts 6 sin/cos per pair to 1.5 amortized.
// Grid: 256 blocks = 64 point-groups (fixed i0, 8 i1, 32 i2 = 256 pts) x
// 4 face-quarters (256 faces). Wave = 16 faces x 256 points; per-thread work
// unchanged (64 pair-units). Cross-quarter combine: atomicAdd into memset'd
// out (R7-proven). Slow pairs: per-lane 64-bit mask, exact-f64 replay
// post-loop (static k indexing), as in R10.

namespace {
constexpr int kNpts = 32 * 32 * 32;   // 32768 frequency points
constexpr int kHalf = kNpts / 2;      // 16384 conj-unique points
constexpr int kNF = 1024;             // faces
constexpr int kThreads = 1024;        // 16 waves
constexpr int kWaves = 16;
constexpr int kFQ = 4;                // face quarters
constexpr int kFPB = kNF / kFQ;       // 256 faces per block
constexpr int kFPWv = kFPB / kWaves;  // 16 faces per wave
constexpr int kBlocks = 64 * kFQ;     // 64 point-groups x 4 quarters
}

__device__ __forceinline__ float fract32(float x) {
#if __has_builtin(__builtin_amdgcn_fractf)
    return __builtin_amdgcn_fractf(x);
#else
    return x - floorf(x);
#endif
}

// exact f64 replica of the reference's pair case value
__device__ __forceinline__ void pair_case_f64(double x1, double x2, double x3,
                                              double& vr, double& vi) {
    const double m = (x1 + x2) * 0.5;
    const double d = m - x3;
    double sm, cm, s3, c3;
    sincos(m, &sm, &cm);
    sincos(x3, &s3, &c3);
    vr = (sm + (cm - c3) / d) / d;
    vi = (cm + (s3 - sm) / d) / d;
}

// Exact f64 replica of the reference region logic for one (face, point) pair.
// Called only AFTER the hot loop.
__device__ __noinline__ void slow_exact(
        int f, int p, const float* __restrict__ verts,
        const float* __restrict__ box, const int* __restrict__ faces,
        const float* __restrict__ xi0, const float* __restrict__ xi1,
        const float* __restrict__ xi2, float& cr, float& ci) {
    const double SEPS = __builtin_sqrt(1.19209e-07);  // matches float(np.sqrt(EPS))
    const double TWO_PI = 6.283185307179586;
    const double INV_TWO_PI = 0.15915494309189535;

    const int i2 = p & 31, i1 = (p >> 5) & 31, i0 = p >> 10;
    const double xxd = (double)xi0[i0] * INV_TWO_PI;
    const double xyd = (double)xi1[i1] * INV_TWO_PI;
    const double xzd = (double)xi2[i2] * INV_TWO_PI;
    const double lo0 = (double)box[0], lo1 = (double)box[2], lo2 = (double)box[4];
    const int ia = faces[3 * f + 0], ib = faces[3 * f + 1], ic = faces[3 * f + 2];
    const double ax = (double)verts[3 * ia + 0] - lo0, ay = (double)verts[3 * ia + 1] - lo1, az = (double)verts[3 * ia + 2] - lo2;
    const double bx = (double)verts[3 * ib + 0] - lo0, by = (double)verts[3 * ib + 1] - lo1, bz = (double)verts[3 * ib + 2] - lo2;
    const double cx = (double)verts[3 * ic + 0] - lo0, cy = (double)verts[3 * ic + 1] - lo1, cz = (double)verts[3 * ic + 2] - lo2;
    // f32 area exactly as the fast-path prep computes it
    const float axf = (float)ax, ayf = (float)ay, azf = (float)az;
    const float bxf = (float)bx, byf = (float)by, bzf = (float)bz;
    const float cxf = (float)cx, cyf = (float)cy, czf = (float)cz;
    const float e1x = bxf - axf, e1y = byf - ayf, e1z = bzf - azf;
    const float e2x = cxf - axf, e2y = cyf - ayf, e2z = czf - azf;
    const float crx = e1y * e2z - e1z * e2y;
    const float cry = e1z * e2x - e1x * e2z;
    const float crz = e1x * e2y - e1y * e2x;
    const float areaf = 0.5f * sqrtf(crx * crx + cry * cry + crz * crz);
    const double rad = fma(xzd, az, fma(xyd, ay, xxd * ax));
    const double rbd = fma(xzd, bz, fma(xyd, by, xxd * bx));
    const double rcd = fma(xzd, cz, fma(xyd, cy, xxd * cx));
    const double xa = rad * TWO_PI, xb = rbd * TWO_PI, xc = rcd * TWO_PI;
    const double dAB = xb - xa, dBC = xc - xb, dCA = xa - xc;
    const double aab = fabs(dAB), abc = fabs(dBC), aca = fabs(dCA);
    const bool s2 = aab < SEPS, s3 = abc < SEPS, s4 = aca < SEPS;
    const bool c2 = aab <= SEPS, c3 = abc <= SEPS, c4 = aca <= SEPS;
    const bool R1 = (s2 && s3) || (s3 && s4) || (s4 && s2);
    const bool R2 = c2 && !R1;
    const bool R3b = c3 && !R2 && !R1;
    const bool R4 = c4 && !R3b && !R2 && !R1;
    double vr, vi;
    if (R1) {
        const double m = ((xa + xb) + xc) / 3.0;
        double sm, cm;
        sincos(m, &sm, &cm);
        vr = cm / 2.0;
        vi = -sm / 2.0;
    } else if (R2) {
        pair_case_f64(xa, xb, xc, vr, vi);
    } else if (R3b) {
        pair_case_f64(xb, xc, xa, vr, vi);
    } else if (R4) {
        pair_case_f64(xc, xa, xb, vr, vi);
    } else {
        double sa, ca, sb, cb, sc, cc;
        sincos(xa, &sa, &ca);
        sincos(xb, &sb, &cb);
        sincos(xc, &sc, &cc);
        const double da = dAB * dCA, db = dBC * dAB, dc = dCA * dBC;
        vr = (ca / da + cb / db) + cc / dc;
        vi = -((sa / da + sb / db) + sc / dc);
    }
    cr = areaf * (float)vr;
    ci = areaf * (float)vi;
}

__global__ __launch_bounds__(kThreads, 4) void fourier_zrec(
        const float* __restrict__ verts, const float* __restrict__ box,
        const int* __restrict__ faces, const float* __restrict__ xi0,
        const float* __restrict__ xi1, const float* __restrict__ xi2,
        float* __restrict__ out, int interleaved) {
    const float INV_TWO_PI_F = 0.15915494f;
    const float TAUP_REV2 = 2.5330296e-5f;  // 1e-3 rad^2 in rev^2 (product gate)

    // rec[f][0]: ax ay az bx | [1]: by bz cx cy | [2]: cz w dsab dsbc
    // [3]: cA sA cB sB       | [4]: cC sC dsca pad
    __shared__ float4 rec[kFPB][5];       // 20 KB
    __shared__ float accR[kWaves][256];   // 16 KB
    __shared__ float accI[kWaves][256];   // 16 KB
    __shared__ float wsum[kWaves];
    __shared__ float meshar_sh;

    const int t = threadIdx.x;
    const int l = t & 63;                 // lane
    const int w = t >> 6;                 // wave -> face subgroup
    const int g = blockIdx.x >> 2;        // point group [0,64)
    const int fq = blockIdx.x & 3;        // face quarter
    const int i0 = g >> 2;                // [0,16)
    const int i1base = (g & 3) * 8;

    // ---- prep: thread t computes face t (area for meshar); the 256 threads
    // whose face is in this quarter also build the rec entry ----
    {
        const int f = t;
        const float lo0 = box[0], lo1 = box[2], lo2 = box[4];
        const int ia = faces[3 * f + 0], ib = faces[3 * f + 1], ic = faces[3 * f + 2];
        const float ax = verts[3 * ia + 0] - lo0, ay = verts[3 * ia + 1] - lo1, az = verts[3 * ia + 2] - lo2;
        const float bx = verts[3 * ib + 0] - lo0, by = verts[3 * ib + 1] - lo1, bz = verts[3 * ib + 2] - lo2;
        const float cx = verts[3 * ic + 0] - lo0, cy = verts[3 * ic + 1] - lo1, cz = verts[3 * ic + 2] - lo2;
        const float e1x = bx - ax, e1y = by - ay, e1z = bz - az;
        const float e2x = cx - ax, e2y = cy - ay, e2z = cz - az;
        const float crx = e1y * e2z - e1z * e2y;
        const float cry = e1z * e2x - e1x * e2z;
        const float crz = e1x * e2y - e1y * e2x;
        const float area = 0.5f * sqrtf(crx * crx + cry * cry + crz * crz);
        if ((f >> 8) == fq) {
            const int r = f & 255;
            // z-step rotation constants: cos/sin(2*pi*fract(vz)) — exact
            const float fa = fract32(az), fb = fract32(bz), fc = fract32(cz);
            const float cA = __builtin_amdgcn_cosf(fa), sA = __builtin_amdgcn_sinf(fa);
            const float cB = __builtin_amdgcn_cosf(fb), sB = __builtin_amdgcn_sinf(fb);
            const float cC = __builtin_amdgcn_cosf(fc), sC = __builtin_amdgcn_sinf(fc);
            rec[r][0] = make_float4(ax, ay, az, bx);
            rec[r][1] = make_float4(by, bz, cx, cy);
            rec[r][2] = make_float4(cz, area * 0.025330296f, bz - az, cz - bz);
            rec[r][3] = make_float4(cA, sA, cB, sB);
            rec[r][4] = make_float4(cC, sC, az - cz, 0.0f);
        }
        float a = area;
        a += __shfl_down(a, 32, 64);
        a += __shfl_down(a, 16, 64);
        a += __shfl_down(a, 8, 64);
        a += __shfl_down(a, 4, 64);
        a += __shfl_down(a, 2, 64);
        a += __shfl_down(a, 1, 64);
        if (l == 0) wsum[w] = a;
    }
    __syncthreads();
    if (t == 0) {
        float s = wsum[0];
#pragma unroll
        for (int j = 1; j < kWaves; ++j) s += wsum[j];
        meshar_sh = s;
    }

    // ---- hot loop: lane owns 4 points (i2 = i2base..+3) of (i0, i1);
    // wave w handles 16 faces ----
    const int i1 = i1base + (l >> 3);
    const int i2base = (l & 7) * 4;
    const float xxr = xi0[i0] * INV_TWO_PI_F;
    const float xyr = xi1[i1] * INV_TWO_PI_F;
    const float xzr0 = xi2[i2base] * INV_TWO_PI_F;

    float re[4] = {0.0f, 0.0f, 0.0f, 0.0f};
    float im[4] = {0.0f, 0.0f, 0.0f, 0.0f};
    unsigned long long slowMask = 0ull;
    const int rbase = w * kFPWv;

#pragma unroll 2
    for (int i = 0; i < kFPWv; ++i) {
        const float4 q0 = rec[rbase + i][0];
        const float4 q1 = rec[rbase + i][1];
        const float4 q2 = rec[rbase + i][2];
        const float4 q3 = rec[rbase + i][3];
        const float4 q4 = rec[rbase + i][4];
        // base-point phases (revolutions)
        const float ra = fmaf(xzr0, q0.z, fmaf(xyr, q0.y, xxr * q0.x));
        const float rb = fmaf(xzr0, q1.y, fmaf(xyr, q1.x, xxr * q0.w));
        const float rc = fmaf(xzr0, q2.x, fmaf(xyr, q1.w, xxr * q1.z));
        float fdab = rb - ra, fdbc = rc - rb, fdca = ra - rc;
        float ca_ = __builtin_amdgcn_cosf(fract32(ra)), sa_ = __builtin_amdgcn_sinf(fract32(ra));
        float cb_ = __builtin_amdgcn_cosf(fract32(rb)), sb_ = __builtin_amdgcn_sinf(fract32(rb));
        float cc_ = __builtin_amdgcn_cosf(fract32(rc)), sc_ = __builtin_amdgcn_sinf(fract32(rc));
        const float wgt = q2.y;
        const float dsab = q2.z, dsbc = q2.w, dsca = q4.z;
        const float cA = q3.x, sA = q3.y, cB = q3.z, sB = q3.w;
        const float cC = q4.x, sC = q4.y;

#pragma unroll
        for (int k = 0; k < 4; ++k) {
            const float d1 = fdab * fdca;
            const float d2 = fdbc * fdab;
            const float d3 = fdca * fdbc;
            const float mn = fminf(fminf(fabsf(d1), fabsf(d2)), fabsf(d3));
            if (mn > TAUP_REV2) {
                const float R3w = __builtin_amdgcn_rcpf(d1 * fdbc) * wgt;
                const float r1 = fdbc * R3w, r2 = fdca * R3w, r3 = fdab * R3w;
                re[k] = fmaf(cc_, r3, fmaf(cb_, r2, fmaf(ca_, r1, re[k])));
                im[k] = fmaf(-sc_, r3, fmaf(-sb_, r2, fmaf(-sa_, r1, im[k])));
            } else {
                slowMask |= (1ull << (i * 4 + k));
            }
            if (k < 3) {
                // advance one i2 step: rotate each vertex phasor, shift diffs
                const float nca = ca_ * cA - sa_ * sA;
                const float nsa = sa_ * cA + ca_ * sA;
                const float ncb = cb_ * cB - sb_ * sB;
                const float nsb = sb_ * cB + cb_ * sB;
                const float ncc = cc_ * cC - sc_ * sC;
                const float nsc = sc_ * cC + cc_ * sC;
                ca_ = nca; sa_ = nsa;
                cb_ = ncb; sb_ = nsb;
                cc_ = ncc; sc_ = nsc;
                fdab += dsab; fdbc += dsbc; fdca += dsca;
            }
        }
    }

    // ---- per-lane exact-f64 replay of slow pairs (static k indexing) ----
    if (slowMask) {
#pragma unroll
        for (int k = 0; k < 4; ++k) {
            unsigned long long m = (slowMask >> k) & 0x1111111111111111ull;
            while (m) {
                const int b = (int)__builtin_ctzll(m);
                m &= m - 1ull;
                const int i = b >> 2;
                const int f = fq * kFPB + rbase + i;
                const int p = (i0 << 10) | (i1 << 5) | (i2base + k);
                float cr, ci;
                slow_exact(f, p, verts, box, faces, xi0, xi1, xi2, cr, ci);
                re[k] += cr;
                im[k] += ci;
            }
        }
    }

    // ---- wave partials into LDS (4 consecutive slots per lane) ----
    const int slotBase = (l >> 3) * 32 + (l & 7) * 4;
    *(float4*)&accR[w][slotBase] = make_float4(re[0], re[1], re[2], re[3]);
    *(float4*)&accI[w][slotBase] = make_float4(im[0], im[1], im[2], im[3]);
    __syncthreads();

    // ---- reduce 16 waves, scale, atomic-add this quarter's contribution ----
    if (t < 256) {
        float R = accR[0][t], I = accI[0][t];
#pragma unroll
        for (int gg = 1; gg < kWaves; ++gg) { R += accR[gg][t]; I += accI[gg][t]; }
        const float inv2 = 2.0f / meshar_sh;
        R *= inv2;
        I *= inv2;
        const int p = (i0 << 10) | ((i1base + (t >> 5)) << 5) | (t & 31);
        const int q = kNpts - 1 - p;
        if (interleaved) {
            atomicAdd(&out[2 * p + 0], R);
            atomicAdd(&out[2 * p + 1], I);
            atomicAdd(&out[2 * q + 0], R);
            atomicAdd(&out[2 * q + 1], -I);
        } else {
            atomicAdd(&out[p], R);
            atomicAdd(&out[q], R);
        }
    }
}

extern "C" void kernel_launch(void* const* d_in, const int* in_sizes, int n_in,
                              void* d_out, int out_size, void* d_ws, size_t ws_size,
                              hipStream_t stream) {
    const float* verts = (const float*)d_in[0];
    const float* box   = (const float*)d_in[1];
    const float* xi0v  = (const float*)d_in[2];
    const float* xi1v  = (const float*)d_in[3];
    const float* xi2v  = (const float*)d_in[4];
    const int*   faces = (const int*)d_in[5];
    (void)d_ws; (void)ws_size;

    const int interleaved = (out_size == 2 * kNpts) ? 1 : 0;

    hipMemsetAsync(d_out, 0, (size_t)out_size * sizeof(float), stream);
    hipLaunchKernelGGL(fourier_zrec, dim3(kBlocks), dim3(kThreads), 0, stream,
                       verts, box, faces, xi0v, xi1v, xi2v,
                       (float*)d_out, interleaved);
}